// Round 23
// baseline (135.579 us; speedup 1.0000x reference)
//
#include <hip/hip_runtime.h>
#include <hip/hip_fp16.h>

typedef _Float16 f16;
typedef unsigned int u32;
typedef _Float16 f16x4 __attribute__((ext_vector_type(4)));
typedef _Float16 f16x8 __attribute__((ext_vector_type(8)));
typedef float f32x4 __attribute__((ext_vector_type(4)));
typedef float f32x16 __attribute__((ext_vector_type(16)));

#define B_  2
#define N_  2048
#define C_  1024
#define H_  16
#define HD_ 64

// ---------------------------------------------------------------- helpers
__device__ __forceinline__ void gload_lds16(const void* g, void* l) {
  __builtin_amdgcn_global_load_lds((const __attribute__((address_space(1))) u32*)g,
                                   (__attribute__((address_space(3))) u32*)l,
                                   16, 0, 0);
}

__device__ __forceinline__ u32 pack_f16(float a, float b) {
  auto h2 = __builtin_amdgcn_cvt_pkrtz(a, b);   // __fp16 ext_vector(2)
  return __builtin_bit_cast(u32, h2);
}

__device__ __forceinline__ float max3f(float a, float b, float c) {
  return fmaxf(fmaxf(a, b), c);   // clang fuses to v_max3_f32
}

// ---------------------------------------------------------------- unified prep kernel
__global__ __launch_bounds__(256) void prep(const float* __restrict__ x,
                                            f16* __restrict__ xh,
                                            const float* __restrict__ px,
                                            const float* __restrict__ py,
                                            const float* __restrict__ psp,
                                            const void* __restrict__ maskPtr,
                                            float* __restrict__ cs_tab,
                                            float* __restrict__ sn_tab,
                                            const float* __restrict__ Wqkv,
                                            const float* __restrict__ Wproj,
                                            f16* __restrict__ Wqkvt,
                                            f16* __restrict__ Wprojt) {
  __shared__ __align__(16) f16 tile[32][34];
  __shared__ int bad;
  const int blk = blockIdx.x;
  const int tid = threadIdx.x;

  if (blk < 2048) {
    const int i = blk * 256 + tid;
    const float4 a = ((const float4*)x)[i * 2];
    const float4 b = ((const float4*)x)[i * 2 + 1];
    f16x8 o = {(f16)a.x, (f16)a.y, (f16)a.z, (f16)a.w,
               (f16)b.x, (f16)b.y, (f16)b.z, (f16)b.w};
    ((f16x8*)xh)[i] = o;
    return;
  }
  if (blk < 2560) {
    if (tid == 0) bad = 0;
    __syncthreads();
    {
      const u32* mw = (const u32*)maskPtr;
      int v = 0;
#pragma unroll
      for (int k = 0; k < 4; ++k) {
        u32 wv_ = mw[tid * 4 + k];
        if (wv_ != 0u && wv_ != 1u && wv_ != 0x3F800000u) v = 1;
      }
      if (v) atomicOr(&bad, 1);
    }
    __syncthreads();
    const int byteMode = bad;
    const int idx = (blk - 2048) * 256 + tid;
    const int j = idx & 31, tn = idx >> 5;
    const bool doRope = byteMode ? (((const unsigned char*)maskPtr)[tn] != 0)
                                 : (((const u32*)maskPtr)[tn] != 0u);
    float c = 1.f, s = 0.f;
    if (doRope) {
      float ph;
      if (j < 12)      ph = px[tn * 12 + j];
      else if (j < 24) ph = py[tn * 12 + (j - 12)];
      else             ph = psp[tn * 8 + (j - 24)];
      c = __cosf(ph);
      s = __sinf(ph);
    }
    cs_tab[idx] = c;
    sn_tab[idx] = s;
    return;
  }
  const int tb = blk - 2560;
  const int bx = tb & 127, by = tb >> 7;
  const float* W;
  f16* Wt;
  int Ccols, c0;
  if (bx < 96) { W = Wqkv;  Wt = Wqkvt;  Ccols = 3072; c0 = bx * 32; }
  else         { W = Wproj; Wt = Wprojt; Ccols = 1024; c0 = (bx - 96) * 32; }
  const int R = 1024;
  const int r0 = by * 32;
  const int tx = tid & 31, ty = tid >> 5;
#pragma unroll
  for (int k = 0; k < 4; ++k)
    tile[ty + 8 * k][tx] = (f16)W[(size_t)(r0 + ty + 8 * k) * Ccols + c0 + tx];
  __syncthreads();
#pragma unroll
  for (int k = 0; k < 4; ++k)
    Wt[(size_t)(c0 + ty + 8 * k) * R + r0 + tx] = tile[tx][ty + 8 * k];
}

// ---------------------------------------------------------------- fused QKV GEMM + bias + rope + split (128x128 tile)
__global__ __launch_bounds__(256) void gemm_qkv(const f16* __restrict__ A,
                                                const f16* __restrict__ Bt,
                                                const float* __restrict__ bias,
                                                const float* __restrict__ cs_tab,
                                                const float* __restrict__ sn_tab,
                                                f16* __restrict__ Qh,
                                                f16* __restrict__ Kh,
                                                f16* __restrict__ Vt) {
  __shared__ __align__(16) f16 smem[128 * 130];
  f16* const As = smem;
  f16* const Bs = smem + 8192;
  const int K = 1024, Ncols = 3072;
  const int tid = threadIdx.x;
  const int lane = tid & 63;
  const int wv = tid >> 6;
  const int wm = wv >> 1, wn = wv & 1;
  const int nTN = Ncols >> 7;
  int bid = blockIdx.x;
  const int cpx = gridDim.x >> 3;
  bid = (bid & 7) * cpx + (bid >> 3);
  const int tM = bid / nTN, tN = bid % nTN;
  const int rowBase = tM << 7, colBase = tN << 7;
  const int cl = lane & 15, cg = lane >> 4;

  f32x4 acc[4][4];
#pragma unroll
  for (int i = 0; i < 4; ++i)
#pragma unroll
    for (int j = 0; j < 4; ++j) acc[i][j] = (f32x4){0.f, 0.f, 0.f, 0.f};

  const int sR = tid >> 3, sC = tid & 7;

  for (int k0 = 0; k0 < K; k0 += 64) {
#pragma unroll
    for (int is = 0; is < 4; ++is) {
      const int r = is * 32 + sR;
      const int sc = sC ^ (r & 7);
      gload_lds16(A + (size_t)(rowBase + r) * K + k0 + sc * 8, As + is * 2048 + tid * 8);
    }
#pragma unroll
    for (int is = 0; is < 4; ++is) {
      const int r = is * 32 + sR;
      const int sc = sC ^ (r & 7);
      gload_lds16(Bt + (size_t)(colBase + r) * K + k0 + sc * 8, Bs + is * 2048 + tid * 8);
    }
    asm volatile("s_waitcnt vmcnt(0)" ::: "memory");
    __syncthreads();

#pragma unroll
    for (int ks = 0; ks < 2; ++ks) {
      f16x8 af[4], bf[4];
#pragma unroll
      for (int m = 0; m < 4; ++m) {
        const int row = wm * 64 + m * 16 + cl;
        const int ck = (ks * 4 + cg) ^ (row & 7);
        af[m] = *(const f16x8*)(As + row * 64 + ck * 8);
      }
#pragma unroll
      for (int n = 0; n < 4; ++n) {
        const int row = wn * 64 + n * 16 + cl;
        const int ck = (ks * 4 + cg) ^ (row & 7);
        bf[n] = *(const f16x8*)(Bs + row * 64 + ck * 8);
      }
#pragma unroll
      for (int m = 0; m < 4; ++m)
#pragma unroll
        for (int n = 0; n < 4; ++n)
          acc[m][n] = __builtin_amdgcn_mfma_f32_16x16x32_f16(af[m], bf[n], acc[m][n], 0, 0, 0);
    }
    __syncthreads();
  }

#pragma unroll
  for (int m = 0; m < 4; ++m)
#pragma unroll
    for (int n = 0; n < 4; ++n) {
      const int lc = wn * 64 + n * 16 + cl;
      const float bz = bias[colBase + lc];
#pragma unroll
      for (int reg = 0; reg < 4; ++reg) {
        const int lr = wm * 64 + m * 16 + cg * 4 + reg;
        smem[lr * 130 + lc] = (f16)(acc[m][n][reg] + bz);
      }
    }
  __syncthreads();

  const int sec = colBase >> 10;
  const int h0 = (colBase & 1023) >> 6;
  const int bb = rowBase >> 11;
  const int nbase = rowBase & 2047;

  if (sec < 2) {
    const int lr = tid >> 1, hh = tid & 1;
    const int n = nbase + lr;
    const int h = h0 + hh;
    const f16* srcrow = smem + lr * 130 + hh * 64;
    float t[64];
#pragma unroll
    for (int c = 0; c < 8; ++c) {
      f16x8 v = *(const f16x8*)(srcrow + c * 8);
#pragma unroll
      for (int j = 0; j < 8; ++j) t[c * 8 + j] = (float)v[j];
    }
    const float* csr = cs_tab + ((size_t)bb * N_ + n) * 32;
    const float* snr = sn_tab + ((size_t)bb * N_ + n) * 32;
    __align__(16) f16 o[64];
#pragma unroll
    for (int d = 0; d < 64; ++d) {
      int j;
      float rot;
      if (d < 24) {
        j = (d < 12) ? d : d - 12;
        rot = (d < 12) ? -t[d + 12] : t[d - 12];
      } else if (d < 48) {
        const int dd = d - 24;
        j = 12 + ((dd < 12) ? dd : dd - 12);
        rot = (dd < 12) ? -t[d + 12] : t[d - 12];
      } else {
        const int dd = d - 48;
        j = 24 + ((dd < 8) ? dd : dd - 8);
        rot = (dd < 8) ? -t[d + 8] : t[d - 8];
      }
      o[d] = (f16)(t[d] * csr[j] + rot * snr[j]);
    }
    f16* dst = (sec == 0 ? Qh : Kh) + (((size_t)(bb * H_ + h)) * N_ + n) * 64;
#pragma unroll
    for (int c = 0; c < 8; ++c) *(f16x8*)(dst + c * 8) = *(const f16x8*)(o + c * 8);
  } else {
    const int pr = tid >> 1, half = tid & 1;
    const int hh = pr >> 6, d = pr & 63;
    const int h = h0 + hh;
    __align__(16) f16 o[64];
#pragma unroll
    for (int i = 0; i < 64; ++i) o[i] = smem[(half * 64 + i) * 130 + hh * 64 + d];
    f16* dst = Vt + (((size_t)(bb * H_ + h)) * 64 + d) * N_ + nbase + half * 64;
#pragma unroll
    for (int c = 0; c < 8; ++c) *(f16x8*)(dst + c * 8) = *(const f16x8*)(o + c * 8);
  }
}

// ---------------------------------------------------------------- GEMM (f32 out) for proj
__global__ __launch_bounds__(256) void gemm_bt_f32(const f16* __restrict__ A,
                                                   const f16* __restrict__ Bt,
                                                   const float* __restrict__ bias,
                                                   float* __restrict__ Cout,
                                                   int M, int N, int K) {
  __shared__ __align__(16) f16 As[128 * 64];
  __shared__ __align__(16) f16 Bs[128 * 64];
  const int tid = threadIdx.x;
  const int lane = tid & 63;
  const int wv = tid >> 6;
  const int wm = wv >> 1, wn = wv & 1;
  const int nTN = N >> 7;
  int bid = blockIdx.x;
  const int cpx = gridDim.x >> 3;
  bid = (bid & 7) * cpx + (bid >> 3);
  const int tM = bid / nTN, tN = bid % nTN;
  const int rowBase = tM << 7, colBase = tN << 7;
  const int cl = lane & 15, cg = lane >> 4;

  f32x4 acc[4][4];
#pragma unroll
  for (int i = 0; i < 4; ++i)
#pragma unroll
    for (int j = 0; j < 4; ++j) acc[i][j] = (f32x4){0.f, 0.f, 0.f, 0.f};

  const int sR = tid >> 3, sC = tid & 7;

  for (int k0 = 0; k0 < K; k0 += 64) {
#pragma unroll
    for (int is = 0; is < 4; ++is) {
      const int r = is * 32 + sR;
      const int sc = sC ^ (r & 7);
      gload_lds16(A + (size_t)(rowBase + r) * K + k0 + sc * 8, As + is * 2048 + tid * 8);
    }
#pragma unroll
    for (int is = 0; is < 4; ++is) {
      const int r = is * 32 + sR;
      const int sc = sC ^ (r & 7);
      gload_lds16(Bt + (size_t)(colBase + r) * K + k0 + sc * 8, Bs + is * 2048 + tid * 8);
    }
    asm volatile("s_waitcnt vmcnt(0)" ::: "memory");
    __syncthreads();

#pragma unroll
    for (int ks = 0; ks < 2; ++ks) {
      f16x8 af[4], bf[4];
#pragma unroll
      for (int m = 0; m < 4; ++m) {
        const int row = wm * 64 + m * 16 + cl;
        const int ck = (ks * 4 + cg) ^ (row & 7);
        af[m] = *(const f16x8*)(As + row * 64 + ck * 8);
      }
#pragma unroll
      for (int n = 0; n < 4; ++n) {
        const int row = wn * 64 + n * 16 + cl;
        const int ck = (ks * 4 + cg) ^ (row & 7);
        bf[n] = *(const f16x8*)(Bs + row * 64 + ck * 8);
      }
#pragma unroll
      for (int m = 0; m < 4; ++m)
#pragma unroll
        for (int n = 0; n < 4; ++n)
          acc[m][n] = __builtin_amdgcn_mfma_f32_16x16x32_f16(af[m], bf[n], acc[m][n], 0, 0, 0);
    }
    __syncthreads();
  }

#pragma unroll
  for (int m = 0; m < 4; ++m) {
#pragma unroll
    for (int n = 0; n < 4; ++n) {
      const int gr0 = rowBase + wm * 64 + m * 16 + cg * 4;
      const int gc = colBase + wn * 64 + n * 16 + cl;
      const float bz = bias[gc];
#pragma unroll
      for (int reg = 0; reg < 4; ++reg)
        Cout[(size_t)(gr0 + reg) * N + gc] = acc[m][n][reg] + bz;
    }
  }
}

// ---------------------------------------------------------------- flash attention v8: MFMA-computed denominator
// r22 structure + l computed on the matrix pipe: accl = mfma(ones, P^T, accl)
// per kk-slice. C-layout col=lane&31=q, all rows identical => accl[0] is the
// full denominator for q=ql; removes ~32 VALU adds/tile + the epilogue shfl.
// Rescale multiplies accl[0] only (its mfma reg-chain is independent).
__global__ __launch_bounds__(512) void attn2(const f16* __restrict__ Qh,
                                             const f16* __restrict__ Kh,
                                             const f16* __restrict__ Vt,
                                             f16* __restrict__ Y) {
  __shared__ __align__(16) f16 lds_flat[3 * 8192];   // 49,152 B
  const int tid = threadIdx.x, lane = tid & 63, w = tid >> 6;   // w in 0..7
  int bid = blockIdx.x;
  bid = (bid & 7) * 32 + (bid >> 3);  // XCD-chunked swizzle (256 % 8 == 0)
  const int bh = bid >> 3, qb = bid & 7;
  const int b = bh >> 4, h = bh & 15;
  const f16* Qb = Qh + (size_t)bh * N_ * 64;
  const f16* Kb = Kh + (size_t)bh * N_ * 64;
  const f16* Vb = Vt + (size_t)bh * 64 * N_;
  const int ql = lane & 31, hi = lane >> 5;

  f16x8 qf[4];
  {
    const int qrow = qb * 256 + w * 32 + ql;
    const f16 scl = (f16)0.125f;
#pragma unroll
    for (int ks = 0; ks < 4; ++ks) {
      f16x8 v = *(const f16x8*)(Qb + (size_t)qrow * 64 + ks * 16 + hi * 8);
#pragma unroll
      for (int j = 0; j < 8; ++j) v[j] *= scl;
      qf[ks] = v;
    }
  }

  const f16x8 ones = {(f16)1, (f16)1, (f16)1, (f16)1, (f16)1, (f16)1, (f16)1, (f16)1};

  f32x16 Of[2];
  f32x16 accl;
#pragma unroll
  for (int d = 0; d < 2; ++d)
#pragma unroll
    for (int r = 0; r < 16; ++r) Of[d][r] = 0.f;
#pragma unroll
  for (int r = 0; r < 16; ++r) accl[r] = 0.f;
  float m_run = -1e30f;

  const int sr = tid >> 3, sc = tid & 7;
#define STAGE(t, bp)                                                                     \
  {                                                                                      \
    const int g = sc ^ (sr & 7);                                                         \
    gload_lds16(Kb + (size_t)((t) * 64 + sr) * 64 + g * 8, (bp) + tid * 8);              \
    gload_lds16(Vb + (size_t)sr * N_ + (t) * 64 + g * 8, (bp) + 4096 + tid * 8);         \
  }

#define CHUNK_MAX(sa, out)                                                               \
  float out;                                                                             \
  {                                                                                      \
    float t0 = max3f(sa[0], sa[1], sa[2]);                                               \
    float t1 = max3f(sa[3], sa[4], sa[5]);                                               \
    float t2 = max3f(sa[6], sa[7], sa[8]);                                               \
    float t3 = max3f(sa[9], sa[10], sa[11]);                                             \
    float t4 = max3f(sa[12], sa[13], sa[14]);                                            \
    out = max3f(max3f(t0, t1, t2), max3f(t3, t4, sa[15]), -1e30f);                       \
  }

#define CHUNK_EXP(sa)                                                                    \
  {                                                                                      \
    _Pragma("unroll") for (int r = 0; r < 16; ++r) sa[r] = __expf(sa[r] - m_run);        \
  }

#define PV_CHUNK(sa, s)                                                                  \
  {                                                                                      \
    u32 pw[8];                                                                           \
    _Pragma("unroll") for (int tt = 0; tt < 8; ++tt)                                     \
      pw[tt] = pack_f16(sa[2 * tt], sa[2 * tt + 1]);                                     \
    _Pragma("unroll") for (int kk = 0; kk < 2; ++kk) {                                   \
      u32 a0 = pw[4 * kk], a1 = pw[4 * kk + 1];                                          \
      u32 b0 = pw[4 * kk + 2], b1 = pw[4 * kk + 3];                                      \
      asm volatile("v_permlane32_swap_b32 %0, %1" : "+v"(a0), "+v"(b0));                 \
      asm volatile("v_permlane32_swap_b32 %0, %1" : "+v"(a1), "+v"(b1));                 \
      union { u32 u[4]; f16x8 v; } pf;                                                   \
      pf.u[0] = a0; pf.u[1] = a1; pf.u[2] = b0; pf.u[3] = b1;                            \
      __builtin_amdgcn_s_setprio(1);                                                     \
      _Pragma("unroll") for (int df = 0; df < 2; ++df) {                                 \
        const int d = df * 32 + ql;                                                      \
        f16x8 vf = *(const f16x8*)(Vs + d * 64 + (((s) * 4 + kk * 2 + hi) ^ (d & 7)) * 8);\
        Of[df] = __builtin_amdgcn_mfma_f32_32x32x16_f16(vf, pf.v, Of[df], 0, 0, 0);      \
      }                                                                                  \
      accl = __builtin_amdgcn_mfma_f32_32x32x16_f16(ones, pf.v, accl, 0, 0, 0);          \
      __builtin_amdgcn_s_setprio(0);                                                     \
    }                                                                                    \
  }

  f16* const base = &lds_flat[0];
  STAGE(0, base);
  STAGE(1, base + 8192);
  asm volatile("s_waitcnt vmcnt(2)" ::: "memory");
  __builtin_amdgcn_s_barrier();

  f16* curp = base;
  f16* stagep = base + 16384;
  for (int t = 0; t < N_ / 64; ++t) {
    if (t < N_ / 64 - 2) STAGE(t + 2, stagep);
    const f16* Ks = curp;
    const f16* Vs = curp + 4096;

    f32x16 sa0, sa1;
#pragma unroll
    for (int r = 0; r < 16; ++r) { sa0[r] = 0.f; sa1[r] = 0.f; }
    const int krow0 = ql, krow1 = 32 + ql;
    __builtin_amdgcn_s_setprio(1);
#pragma unroll
    for (int ks = 0; ks < 4; ++ks) {
      f16x8 kf = *(const f16x8*)(Ks + krow0 * 64 + ((ks * 2 + hi) ^ (krow0 & 7)) * 8);
      sa0 = __builtin_amdgcn_mfma_f32_32x32x16_f16(kf, qf[ks], sa0, 0, 0, 0);
    }
#pragma unroll
    for (int ks = 0; ks < 4; ++ks) {
      f16x8 kf = *(const f16x8*)(Ks + krow1 * 64 + ((ks * 2 + hi) ^ (krow1 & 7)) * 8);
      sa1 = __builtin_amdgcn_mfma_f32_32x32x16_f16(kf, qf[ks], sa1, 0, 0, 0);
    }
    __builtin_amdgcn_s_setprio(0);

    // merged softmax: one shared m per 64-key tile
    CHUNK_MAX(sa0, p0);
    CHUNK_MAX(sa1, p1);
    float pmax = fmaxf(p0, p1);
    pmax = fmaxf(pmax, __shfl_xor(pmax, 32));
    if (__any(pmax > m_run + 8.0f)) {
      const float mnew = fmaxf(m_run, pmax);
      const float corr = __expf(m_run - mnew);
      accl[0] *= corr;
#pragma unroll
      for (int d = 0; d < 2; ++d)
#pragma unroll
        for (int r = 0; r < 16; ++r) Of[d][r] *= corr;
      m_run = mnew;
    }
    CHUNK_EXP(sa0);
    CHUNK_EXP(sa1);

    PV_CHUNK(sa0, 0);
    PV_CHUNK(sa1, 1);

    if (t < N_ / 64 - 2)
      asm volatile("s_waitcnt vmcnt(2) lgkmcnt(0)" ::: "memory");
    else if (t < N_ / 64 - 1)
      asm volatile("s_waitcnt vmcnt(0) lgkmcnt(0)" ::: "memory");
    else
      asm volatile("s_waitcnt lgkmcnt(0)" ::: "memory");
    __builtin_amdgcn_s_barrier();
    curp = (curp == base + 16384) ? base : curp + 8192;
    stagep = (stagep == base + 16384) ? base : stagep + 8192;
  }

  // epilogue: accl[0] = full denominator for q=ql (no cross-half reduce needed)
  const float inv = 1.0f / accl[0];
  f16* Ow = base + w * (32 * 72);
#pragma unroll
  for (int df = 0; df < 2; ++df)
#pragma unroll
    for (int g = 0; g < 4; ++g) {
      f16x4 ov;
#pragma unroll
      for (int e = 0; e < 4; ++e) ov[e] = (f16)(Of[df][g * 4 + e] * inv);
      *(f16x4*)(Ow + ql * 72 + df * 32 + g * 8 + hi * 4) = ov;
    }
  __syncthreads();
  const int rr = lane >> 1, half = lane & 1;
  const f16* srcp = Ow + rr * 72 + half * 32;
  const int nglob = qb * 256 + w * 32 + rr;
  f16* dst = Y + ((size_t)b * N_ + nglob) * C_ + h * 64 + half * 32;
#pragma unroll
  for (int c2 = 0; c2 < 4; ++c2)
    *(f16x8*)(dst + c2 * 8) = *(const f16x8*)(srcp + c2 * 8);
}

// ---------------------------------------------------------------- launch
extern "C" void kernel_launch(void* const* d_in, const int* in_sizes, int n_in,
                              void* d_out, int out_size, void* d_ws, size_t ws_size,
                              hipStream_t stream) {
  const float* x = (const float*)d_in[0];
  const float* px = (const float*)d_in[1];
  const float* py = (const float*)d_in[2];
  const float* psp = (const float*)d_in[3];
  const void* mask = (const void*)d_in[4];
  const float* Wqkv = (const float*)d_in[5];
  const float* bqkv = (const float*)d_in[6];
  const float* Wproj = (const float*)d_in[7];
  const float* bproj = (const float*)d_in[8];
  float* out = (float*)d_out;
  char* ws = (char*)d_ws;

  f16* xh     = (f16*)(ws + 0);           //  8,388,608
  f16* Wqkvt  = (f16*)(ws + 8388608);     //  6,291,456
  f16* Wprojt = (f16*)(ws + 14680064);    //  2,097,152
  f16* Qh     = (f16*)(ws + 41943040);    //  8,388,608
  f16* Kh     = (f16*)(ws + 50331648);    //  8,388,608
  f16* Vt     = (f16*)(ws + 58720256);    //  8,388,608
  f16* Yh     = (f16*)(ws + 67108864);    //  8,388,608
  float* cs_tab = (float*)(ws + 16777216);             // 524,288
  float* sn_tab = (float*)(ws + 17301504);             // 524,288

  prep<<<2048 + 512 + 4096, 256, 0, stream>>>(x, xh, px, py, psp, mask,
                                              cs_tab, sn_tab, Wqkv, Wproj,
                                              Wqkvt, Wprojt);
  gemm_qkv<<<(4096 / 128) * (3072 / 128), 256, 0, stream>>>(
      xh, Wqkvt, bqkv, cs_tab, sn_tab, Qh, Kh, Vt);
  attn2<<<256, 512, 0, stream>>>(Qh, Kh, Vt, Yh);
  gemm_bt_f32<<<(4096 / 128) * (1024 / 128), 256, 0, stream>>>(
      Yh, Wprojt, bproj, out, 4096, 1024, 1024);
}

// Round 24
// 131.498 us; speedup vs baseline: 1.0310x; 1.0310x over previous
//
#include <hip/hip_runtime.h>
#include <hip/hip_fp16.h>

typedef _Float16 f16;
typedef unsigned int u32;
typedef _Float16 f16x4 __attribute__((ext_vector_type(4)));
typedef _Float16 f16x8 __attribute__((ext_vector_type(8)));
typedef float f32x4 __attribute__((ext_vector_type(4)));
typedef float f32x16 __attribute__((ext_vector_type(16)));

#define B_  2
#define N_  2048
#define C_  1024
#define H_  16
#define HD_ 64

// ---------------------------------------------------------------- helpers
__device__ __forceinline__ void gload_lds16(const void* g, void* l) {
  __builtin_amdgcn_global_load_lds((const __attribute__((address_space(1))) u32*)g,
                                   (__attribute__((address_space(3))) u32*)l,
                                   16, 0, 0);
}

__device__ __forceinline__ u32 pack_f16(float a, float b) {
  auto h2 = __builtin_amdgcn_cvt_pkrtz(a, b);   // __fp16 ext_vector(2)
  return __builtin_bit_cast(u32, h2);
}

__device__ __forceinline__ float max3f(float a, float b, float c) {
  return fmaxf(fmaxf(a, b), c);   // clang fuses to v_max3_f32
}

// ---------------------------------------------------------------- unified prep kernel
__global__ __launch_bounds__(256) void prep(const float* __restrict__ x,
                                            f16* __restrict__ xh,
                                            const float* __restrict__ px,
                                            const float* __restrict__ py,
                                            const float* __restrict__ psp,
                                            const void* __restrict__ maskPtr,
                                            float* __restrict__ cs_tab,
                                            float* __restrict__ sn_tab,
                                            const float* __restrict__ Wqkv,
                                            const float* __restrict__ Wproj,
                                            f16* __restrict__ Wqkvt,
                                            f16* __restrict__ Wprojt) {
  __shared__ __align__(16) f16 tile[32][34];
  __shared__ int bad;
  const int blk = blockIdx.x;
  const int tid = threadIdx.x;

  if (blk < 2048) {
    const int i = blk * 256 + tid;
    const float4 a = ((const float4*)x)[i * 2];
    const float4 b = ((const float4*)x)[i * 2 + 1];
    f16x8 o = {(f16)a.x, (f16)a.y, (f16)a.z, (f16)a.w,
               (f16)b.x, (f16)b.y, (f16)b.z, (f16)b.w};
    ((f16x8*)xh)[i] = o;
    return;
  }
  if (blk < 2560) {
    if (tid == 0) bad = 0;
    __syncthreads();
    {
      const u32* mw = (const u32*)maskPtr;
      int v = 0;
#pragma unroll
      for (int k = 0; k < 4; ++k) {
        u32 wv_ = mw[tid * 4 + k];
        if (wv_ != 0u && wv_ != 1u && wv_ != 0x3F800000u) v = 1;
      }
      if (v) atomicOr(&bad, 1);
    }
    __syncthreads();
    const int byteMode = bad;
    const int idx = (blk - 2048) * 256 + tid;
    const int j = idx & 31, tn = idx >> 5;
    const bool doRope = byteMode ? (((const unsigned char*)maskPtr)[tn] != 0)
                                 : (((const u32*)maskPtr)[tn] != 0u);
    float c = 1.f, s = 0.f;
    if (doRope) {
      float ph;
      if (j < 12)      ph = px[tn * 12 + j];
      else if (j < 24) ph = py[tn * 12 + (j - 12)];
      else             ph = psp[tn * 8 + (j - 24)];
      c = __cosf(ph);
      s = __sinf(ph);
    }
    cs_tab[idx] = c;
    sn_tab[idx] = s;
    return;
  }
  const int tb = blk - 2560;
  const int bx = tb & 127, by = tb >> 7;
  const float* W;
  f16* Wt;
  int Ccols, c0;
  if (bx < 96) { W = Wqkv;  Wt = Wqkvt;  Ccols = 3072; c0 = bx * 32; }
  else         { W = Wproj; Wt = Wprojt; Ccols = 1024; c0 = (bx - 96) * 32; }
  const int R = 1024;
  const int r0 = by * 32;
  const int tx = tid & 31, ty = tid >> 5;
#pragma unroll
  for (int k = 0; k < 4; ++k)
    tile[ty + 8 * k][tx] = (f16)W[(size_t)(r0 + ty + 8 * k) * Ccols + c0 + tx];
  __syncthreads();
#pragma unroll
  for (int k = 0; k < 4; ++k)
    Wt[(size_t)(c0 + ty + 8 * k) * R + r0 + tx] = tile[tx][ty + 8 * k];
}

// ---------------------------------------------------------------- fused QKV GEMM + bias + rope + split (128x128 tile)
__global__ __launch_bounds__(256) void gemm_qkv(const f16* __restrict__ A,
                                                const f16* __restrict__ Bt,
                                                const float* __restrict__ bias,
                                                const float* __restrict__ cs_tab,
                                                const float* __restrict__ sn_tab,
                                                f16* __restrict__ Qh,
                                                f16* __restrict__ Kh,
                                                f16* __restrict__ Vt) {
  __shared__ __align__(16) f16 smem[128 * 130];
  f16* const As = smem;
  f16* const Bs = smem + 8192;
  const int K = 1024, Ncols = 3072;
  const int tid = threadIdx.x;
  const int lane = tid & 63;
  const int wv = tid >> 6;
  const int wm = wv >> 1, wn = wv & 1;
  const int nTN = Ncols >> 7;
  int bid = blockIdx.x;
  const int cpx = gridDim.x >> 3;
  bid = (bid & 7) * cpx + (bid >> 3);
  const int tM = bid / nTN, tN = bid % nTN;
  const int rowBase = tM << 7, colBase = tN << 7;
  const int cl = lane & 15, cg = lane >> 4;

  f32x4 acc[4][4];
#pragma unroll
  for (int i = 0; i < 4; ++i)
#pragma unroll
    for (int j = 0; j < 4; ++j) acc[i][j] = (f32x4){0.f, 0.f, 0.f, 0.f};

  const int sR = tid >> 3, sC = tid & 7;

#pragma unroll 2
  for (int k0 = 0; k0 < K; k0 += 64) {
#pragma unroll
    for (int is = 0; is < 4; ++is) {
      const int r = is * 32 + sR;
      const int sc = sC ^ (r & 7);
      gload_lds16(A + (size_t)(rowBase + r) * K + k0 + sc * 8, As + is * 2048 + tid * 8);
    }
#pragma unroll
    for (int is = 0; is < 4; ++is) {
      const int r = is * 32 + sR;
      const int sc = sC ^ (r & 7);
      gload_lds16(Bt + (size_t)(colBase + r) * K + k0 + sc * 8, Bs + is * 2048 + tid * 8);
    }
    asm volatile("s_waitcnt vmcnt(0)" ::: "memory");
    __syncthreads();

#pragma unroll
    for (int ks = 0; ks < 2; ++ks) {
      f16x8 af[4], bf[4];
#pragma unroll
      for (int m = 0; m < 4; ++m) {
        const int row = wm * 64 + m * 16 + cl;
        const int ck = (ks * 4 + cg) ^ (row & 7);
        af[m] = *(const f16x8*)(As + row * 64 + ck * 8);
      }
#pragma unroll
      for (int n = 0; n < 4; ++n) {
        const int row = wn * 64 + n * 16 + cl;
        const int ck = (ks * 4 + cg) ^ (row & 7);
        bf[n] = *(const f16x8*)(Bs + row * 64 + ck * 8);
      }
#pragma unroll
      for (int m = 0; m < 4; ++m)
#pragma unroll
        for (int n = 0; n < 4; ++n)
          acc[m][n] = __builtin_amdgcn_mfma_f32_16x16x32_f16(af[m], bf[n], acc[m][n], 0, 0, 0);
    }
    __syncthreads();
  }

#pragma unroll
  for (int m = 0; m < 4; ++m)
#pragma unroll
    for (int n = 0; n < 4; ++n) {
      const int lc = wn * 64 + n * 16 + cl;
      const float bz = bias[colBase + lc];
#pragma unroll
      for (int reg = 0; reg < 4; ++reg) {
        const int lr = wm * 64 + m * 16 + cg * 4 + reg;
        smem[lr * 130 + lc] = (f16)(acc[m][n][reg] + bz);
      }
    }
  __syncthreads();

  const int sec = colBase >> 10;
  const int h0 = (colBase & 1023) >> 6;
  const int bb = rowBase >> 11;
  const int nbase = rowBase & 2047;

  if (sec < 2) {
    const int lr = tid >> 1, hh = tid & 1;
    const int n = nbase + lr;
    const int h = h0 + hh;
    const f16* srcrow = smem + lr * 130 + hh * 64;
    float t[64];
#pragma unroll
    for (int c = 0; c < 8; ++c) {
      f16x8 v = *(const f16x8*)(srcrow + c * 8);
#pragma unroll
      for (int j = 0; j < 8; ++j) t[c * 8 + j] = (float)v[j];
    }
    const float* csr = cs_tab + ((size_t)bb * N_ + n) * 32;
    const float* snr = sn_tab + ((size_t)bb * N_ + n) * 32;
    __align__(16) f16 o[64];
#pragma unroll
    for (int d = 0; d < 64; ++d) {
      int j;
      float rot;
      if (d < 24) {
        j = (d < 12) ? d : d - 12;
        rot = (d < 12) ? -t[d + 12] : t[d - 12];
      } else if (d < 48) {
        const int dd = d - 24;
        j = 12 + ((dd < 12) ? dd : dd - 12);
        rot = (dd < 12) ? -t[d + 12] : t[d - 12];
      } else {
        const int dd = d - 48;
        j = 24 + ((dd < 8) ? dd : dd - 8);
        rot = (dd < 8) ? -t[d + 8] : t[d - 8];
      }
      o[d] = (f16)(t[d] * csr[j] + rot * snr[j]);
    }
    f16* dst = (sec == 0 ? Qh : Kh) + (((size_t)(bb * H_ + h)) * N_ + n) * 64;
#pragma unroll
    for (int c = 0; c < 8; ++c) *(f16x8*)(dst + c * 8) = *(const f16x8*)(o + c * 8);
  } else {
    const int pr = tid >> 1, half = tid & 1;
    const int hh = pr >> 6, d = pr & 63;
    const int h = h0 + hh;
    __align__(16) f16 o[64];
#pragma unroll
    for (int i = 0; i < 64; ++i) o[i] = smem[(half * 64 + i) * 130 + hh * 64 + d];
    f16* dst = Vt + (((size_t)(bb * H_ + h)) * 64 + d) * N_ + nbase + half * 64;
#pragma unroll
    for (int c = 0; c < 8; ++c) *(f16x8*)(dst + c * 8) = *(const f16x8*)(o + c * 8);
  }
}

// ---------------------------------------------------------------- GEMM (f32 out) for proj
__global__ __launch_bounds__(256) void gemm_bt_f32(const f16* __restrict__ A,
                                                   const f16* __restrict__ Bt,
                                                   const float* __restrict__ bias,
                                                   float* __restrict__ Cout,
                                                   int M, int N, int K) {
  __shared__ __align__(16) f16 As[128 * 64];
  __shared__ __align__(16) f16 Bs[128 * 64];
  const int tid = threadIdx.x;
  const int lane = tid & 63;
  const int wv = tid >> 6;
  const int wm = wv >> 1, wn = wv & 1;
  const int nTN = N >> 7;
  int bid = blockIdx.x;
  const int cpx = gridDim.x >> 3;
  bid = (bid & 7) * cpx + (bid >> 3);
  const int tM = bid / nTN, tN = bid % nTN;
  const int rowBase = tM << 7, colBase = tN << 7;
  const int cl = lane & 15, cg = lane >> 4;

  f32x4 acc[4][4];
#pragma unroll
  for (int i = 0; i < 4; ++i)
#pragma unroll
    for (int j = 0; j < 4; ++j) acc[i][j] = (f32x4){0.f, 0.f, 0.f, 0.f};

  const int sR = tid >> 3, sC = tid & 7;

#pragma unroll 2
  for (int k0 = 0; k0 < K; k0 += 64) {
#pragma unroll
    for (int is = 0; is < 4; ++is) {
      const int r = is * 32 + sR;
      const int sc = sC ^ (r & 7);
      gload_lds16(A + (size_t)(rowBase + r) * K + k0 + sc * 8, As + is * 2048 + tid * 8);
    }
#pragma unroll
    for (int is = 0; is < 4; ++is) {
      const int r = is * 32 + sR;
      const int sc = sC ^ (r & 7);
      gload_lds16(Bt + (size_t)(colBase + r) * K + k0 + sc * 8, Bs + is * 2048 + tid * 8);
    }
    asm volatile("s_waitcnt vmcnt(0)" ::: "memory");
    __syncthreads();

#pragma unroll
    for (int ks = 0; ks < 2; ++ks) {
      f16x8 af[4], bf[4];
#pragma unroll
      for (int m = 0; m < 4; ++m) {
        const int row = wm * 64 + m * 16 + cl;
        const int ck = (ks * 4 + cg) ^ (row & 7);
        af[m] = *(const f16x8*)(As + row * 64 + ck * 8);
      }
#pragma unroll
      for (int n = 0; n < 4; ++n) {
        const int row = wn * 64 + n * 16 + cl;
        const int ck = (ks * 4 + cg) ^ (row & 7);
        bf[n] = *(const f16x8*)(Bs + row * 64 + ck * 8);
      }
#pragma unroll
      for (int m = 0; m < 4; ++m)
#pragma unroll
        for (int n = 0; n < 4; ++n)
          acc[m][n] = __builtin_amdgcn_mfma_f32_16x16x32_f16(af[m], bf[n], acc[m][n], 0, 0, 0);
    }
    __syncthreads();
  }

#pragma unroll
  for (int m = 0; m < 4; ++m) {
#pragma unroll
    for (int n = 0; n < 4; ++n) {
      const int gr0 = rowBase + wm * 64 + m * 16 + cg * 4;
      const int gc = colBase + wn * 64 + n * 16 + cl;
      const float bz = bias[gc];
#pragma unroll
      for (int reg = 0; reg < 4; ++reg)
        Cout[(size_t)(gr0 + reg) * N + gc] = acc[m][n][reg] + bz;
    }
  }
}

// ---------------------------------------------------------------- flash attention v8 (r23, passing, 57.1us)
__global__ __launch_bounds__(512) void attn2(const f16* __restrict__ Qh,
                                             const f16* __restrict__ Kh,
                                             const f16* __restrict__ Vt,
                                             f16* __restrict__ Y) {
  __shared__ __align__(16) f16 lds_flat[3 * 8192];   // 49,152 B
  const int tid = threadIdx.x, lane = tid & 63, w = tid >> 6;   // w in 0..7
  int bid = blockIdx.x;
  bid = (bid & 7) * 32 + (bid >> 3);  // XCD-chunked swizzle (256 % 8 == 0)
  const int bh = bid >> 3, qb = bid & 7;
  const int b = bh >> 4, h = bh & 15;
  const f16* Qb = Qh + (size_t)bh * N_ * 64;
  const f16* Kb = Kh + (size_t)bh * N_ * 64;
  const f16* Vb = Vt + (size_t)bh * 64 * N_;
  const int ql = lane & 31, hi = lane >> 5;

  f16x8 qf[4];
  {
    const int qrow = qb * 256 + w * 32 + ql;
    const f16 scl = (f16)0.125f;
#pragma unroll
    for (int ks = 0; ks < 4; ++ks) {
      f16x8 v = *(const f16x8*)(Qb + (size_t)qrow * 64 + ks * 16 + hi * 8);
#pragma unroll
      for (int j = 0; j < 8; ++j) v[j] *= scl;
      qf[ks] = v;
    }
  }

  const f16x8 ones = {(f16)1, (f16)1, (f16)1, (f16)1, (f16)1, (f16)1, (f16)1, (f16)1};

  f32x16 Of[2];
  f32x16 accl;
#pragma unroll
  for (int d = 0; d < 2; ++d)
#pragma unroll
    for (int r = 0; r < 16; ++r) Of[d][r] = 0.f;
#pragma unroll
  for (int r = 0; r < 16; ++r) accl[r] = 0.f;
  float m_run = -1e30f;

  const int sr = tid >> 3, sc = tid & 7;
#define STAGE(t, bp)                                                                     \
  {                                                                                      \
    const int g = sc ^ (sr & 7);                                                         \
    gload_lds16(Kb + (size_t)((t) * 64 + sr) * 64 + g * 8, (bp) + tid * 8);              \
    gload_lds16(Vb + (size_t)sr * N_ + (t) * 64 + g * 8, (bp) + 4096 + tid * 8);         \
  }

#define CHUNK_MAX(sa, out)                                                               \
  float out;                                                                             \
  {                                                                                      \
    float t0 = max3f(sa[0], sa[1], sa[2]);                                               \
    float t1 = max3f(sa[3], sa[4], sa[5]);                                               \
    float t2 = max3f(sa[6], sa[7], sa[8]);                                               \
    float t3 = max3f(sa[9], sa[10], sa[11]);                                             \
    float t4 = max3f(sa[12], sa[13], sa[14]);                                            \
    out = max3f(max3f(t0, t1, t2), max3f(t3, t4, sa[15]), -1e30f);                       \
  }

#define CHUNK_EXP(sa)                                                                    \
  {                                                                                      \
    _Pragma("unroll") for (int r = 0; r < 16; ++r) sa[r] = __expf(sa[r] - m_run);        \
  }

#define PV_CHUNK(sa, s)                                                                  \
  {                                                                                      \
    u32 pw[8];                                                                           \
    _Pragma("unroll") for (int tt = 0; tt < 8; ++tt)                                     \
      pw[tt] = pack_f16(sa[2 * tt], sa[2 * tt + 1]);                                     \
    _Pragma("unroll") for (int kk = 0; kk < 2; ++kk) {                                   \
      u32 a0 = pw[4 * kk], a1 = pw[4 * kk + 1];                                          \
      u32 b0 = pw[4 * kk + 2], b1 = pw[4 * kk + 3];                                      \
      asm volatile("v_permlane32_swap_b32 %0, %1" : "+v"(a0), "+v"(b0));                 \
      asm volatile("v_permlane32_swap_b32 %0, %1" : "+v"(a1), "+v"(b1));                 \
      union { u32 u[4]; f16x8 v; } pf;                                                   \
      pf.u[0] = a0; pf.u[1] = a1; pf.u[2] = b0; pf.u[3] = b1;                            \
      __builtin_amdgcn_s_setprio(1);                                                     \
      _Pragma("unroll") for (int df = 0; df < 2; ++df) {                                 \
        const int d = df * 32 + ql;                                                      \
        f16x8 vf = *(const f16x8*)(Vs + d * 64 + (((s) * 4 + kk * 2 + hi) ^ (d & 7)) * 8);\
        Of[df] = __builtin_amdgcn_mfma_f32_32x32x16_f16(vf, pf.v, Of[df], 0, 0, 0);      \
      }                                                                                  \
      accl = __builtin_amdgcn_mfma_f32_32x32x16_f16(ones, pf.v, accl, 0, 0, 0);          \
      __builtin_amdgcn_s_setprio(0);                                                     \
    }                                                                                    \
  }

  f16* const base = &lds_flat[0];
  STAGE(0, base);
  STAGE(1, base + 8192);
  asm volatile("s_waitcnt vmcnt(2)" ::: "memory");
  __builtin_amdgcn_s_barrier();

  f16* curp = base;
  f16* stagep = base + 16384;
  for (int t = 0; t < N_ / 64; ++t) {
    if (t < N_ / 64 - 2) STAGE(t + 2, stagep);
    const f16* Ks = curp;
    const f16* Vs = curp + 4096;

    f32x16 sa0, sa1;
#pragma unroll
    for (int r = 0; r < 16; ++r) { sa0[r] = 0.f; sa1[r] = 0.f; }
    const int krow0 = ql, krow1 = 32 + ql;
    __builtin_amdgcn_s_setprio(1);
#pragma unroll
    for (int ks = 0; ks < 4; ++ks) {
      f16x8 kf = *(const f16x8*)(Ks + krow0 * 64 + ((ks * 2 + hi) ^ (krow0 & 7)) * 8);
      sa0 = __builtin_amdgcn_mfma_f32_32x32x16_f16(kf, qf[ks], sa0, 0, 0, 0);
    }
#pragma unroll
    for (int ks = 0; ks < 4; ++ks) {
      f16x8 kf = *(const f16x8*)(Ks + krow1 * 64 + ((ks * 2 + hi) ^ (krow1 & 7)) * 8);
      sa1 = __builtin_amdgcn_mfma_f32_32x32x16_f16(kf, qf[ks], sa1, 0, 0, 0);
    }
    __builtin_amdgcn_s_setprio(0);

    CHUNK_MAX(sa0, p0);
    CHUNK_MAX(sa1, p1);
    float pmax = fmaxf(p0, p1);
    pmax = fmaxf(pmax, __shfl_xor(pmax, 32));
    if (__any(pmax > m_run + 8.0f)) {
      const float mnew = fmaxf(m_run, pmax);
      const float corr = __expf(m_run - mnew);
      accl[0] *= corr;
#pragma unroll
      for (int d = 0; d < 2; ++d)
#pragma unroll
        for (int r = 0; r < 16; ++r) Of[d][r] *= corr;
      m_run = mnew;
    }
    CHUNK_EXP(sa0);
    CHUNK_EXP(sa1);

    PV_CHUNK(sa0, 0);
    PV_CHUNK(sa1, 1);

    if (t < N_ / 64 - 2)
      asm volatile("s_waitcnt vmcnt(2) lgkmcnt(0)" ::: "memory");
    else if (t < N_ / 64 - 1)
      asm volatile("s_waitcnt vmcnt(0) lgkmcnt(0)" ::: "memory");
    else
      asm volatile("s_waitcnt lgkmcnt(0)" ::: "memory");
    __builtin_amdgcn_s_barrier();
    curp = (curp == base + 16384) ? base : curp + 8192;
    stagep = (stagep == base + 16384) ? base : stagep + 8192;
  }

  const float inv = 1.0f / accl[0];
  f16* Ow = base + w * (32 * 72);
#pragma unroll
  for (int df = 0; df < 2; ++df)
#pragma unroll
    for (int g = 0; g < 4; ++g) {
      f16x4 ov;
#pragma unroll
      for (int e = 0; e < 4; ++e) ov[e] = (f16)(Of[df][g * 4 + e] * inv);
      *(f16x4*)(Ow + ql * 72 + df * 32 + g * 8 + hi * 4) = ov;
    }
  __syncthreads();
  const int rr = lane >> 1, half = lane & 1;
  const f16* srcp = Ow + rr * 72 + half * 32;
  const int nglob = qb * 256 + w * 32 + rr;
  f16* dst = Y + ((size_t)b * N_ + nglob) * C_ + h * 64 + half * 32;
#pragma unroll
  for (int c2 = 0; c2 < 4; ++c2)
    *(f16x8*)(dst + c2 * 8) = *(const f16x8*)(srcp + c2 * 8);
}

// ---------------------------------------------------------------- launch
extern "C" void kernel_launch(void* const* d_in, const int* in_sizes, int n_in,
                              void* d_out, int out_size, void* d_ws, size_t ws_size,
                              hipStream_t stream) {
  const float* x = (const float*)d_in[0];
  const float* px = (const float*)d_in[1];
  const float* py = (const float*)d_in[2];
  const float* psp = (const float*)d_in[3];
  const void* mask = (const void*)d_in[4];
  const float* Wqkv = (const float*)d_in[5];
  const float* bqkv = (const float*)d_in[6];
  const float* Wproj = (const float*)d_in[7];
  const float* bproj = (const float*)d_in[8];
  float* out = (float*)d_out;
  char* ws = (char*)d_ws;

  f16* xh     = (f16*)(ws + 0);           //  8,388,608
  f16* Wqkvt  = (f16*)(ws + 8388608);     //  6,291,456
  f16* Wprojt = (f16*)(ws + 14680064);    //  2,097,152
  f16* Qh     = (f16*)(ws + 41943040);    //  8,388,608
  f16* Kh     = (f16*)(ws + 50331648);    //  8,388,608
  f16* Vt     = (f16*)(ws + 58720256);    //  8,388,608
  f16* Yh     = (f16*)(ws + 67108864);    //  8,388,608
  float* cs_tab = (float*)(ws + 16777216);             // 524,288
  float* sn_tab = (float*)(ws + 17301504);             // 524,288

  prep<<<2048 + 512 + 4096, 256, 0, stream>>>(x, xh, px, py, psp, mask,
                                              cs_tab, sn_tab, Wqkv, Wproj,
                                              Wqkvt, Wprojt);
  gemm_qkv<<<(4096 / 128) * (3072 / 128), 256, 0, stream>>>(
      xh, Wqkvt, bqkv, cs_tab, sn_tab, Qh, Kh, Vt);
  attn2<<<256, 512, 0, stream>>>(Qh, Kh, Vt, Yh);
  gemm_bt_f32<<<(4096 / 128) * (1024 / 128), 256, 0, stream>>>(
      Yh, Wprojt, bproj, out, 4096, 1024, 1024);
}

// Round 25
// 130.318 us; speedup vs baseline: 1.0404x; 1.0091x over previous
//
#include <hip/hip_runtime.h>
#include <hip/hip_fp16.h>

typedef _Float16 f16;
typedef unsigned int u32;
typedef _Float16 f16x4 __attribute__((ext_vector_type(4)));
typedef _Float16 f16x8 __attribute__((ext_vector_type(8)));
typedef float f32x4 __attribute__((ext_vector_type(4)));
typedef float f32x16 __attribute__((ext_vector_type(16)));

#define B_  2
#define N_  2048
#define C_  1024
#define H_  16
#define HD_ 64

// ---------------------------------------------------------------- helpers
__device__ __forceinline__ void gload_lds16(const void* g, void* l) {
  __builtin_amdgcn_global_load_lds((const __attribute__((address_space(1))) u32*)g,
                                   (__attribute__((address_space(3))) u32*)l,
                                   16, 0, 0);
}

__device__ __forceinline__ u32 pack_f16(float a, float b) {
  auto h2 = __builtin_amdgcn_cvt_pkrtz(a, b);   // __fp16 ext_vector(2)
  return __builtin_bit_cast(u32, h2);
}

__device__ __forceinline__ float max3f(float a, float b, float c) {
  return fmaxf(fmaxf(a, b), c);   // clang fuses to v_max3_f32
}

// ---------------------------------------------------------------- unified prep kernel
__global__ __launch_bounds__(256) void prep(const float* __restrict__ x,
                                            f16* __restrict__ xh,
                                            const float* __restrict__ px,
                                            const float* __restrict__ py,
                                            const float* __restrict__ psp,
                                            const void* __restrict__ maskPtr,
                                            float* __restrict__ cs_tab,
                                            float* __restrict__ sn_tab,
                                            const float* __restrict__ Wqkv,
                                            const float* __restrict__ Wproj,
                                            f16* __restrict__ Wqkvt,
                                            f16* __restrict__ Wprojt) {
  __shared__ __align__(16) f16 tile[32][34];
  __shared__ int bad;
  const int blk = blockIdx.x;
  const int tid = threadIdx.x;

  if (blk < 2048) {
    const int i = blk * 256 + tid;
    const float4 a = ((const float4*)x)[i * 2];
    const float4 b = ((const float4*)x)[i * 2 + 1];
    f16x8 o = {(f16)a.x, (f16)a.y, (f16)a.z, (f16)a.w,
               (f16)b.x, (f16)b.y, (f16)b.z, (f16)b.w};
    ((f16x8*)xh)[i] = o;
    return;
  }
  if (blk < 2560) {
    if (tid == 0) bad = 0;
    __syncthreads();
    {
      const u32* mw = (const u32*)maskPtr;
      int v = 0;
#pragma unroll
      for (int k = 0; k < 4; ++k) {
        u32 wv_ = mw[tid * 4 + k];
        if (wv_ != 0u && wv_ != 1u && wv_ != 0x3F800000u) v = 1;
      }
      if (v) atomicOr(&bad, 1);
    }
    __syncthreads();
    const int byteMode = bad;
    const int idx = (blk - 2048) * 256 + tid;
    const int j = idx & 31, tn = idx >> 5;
    const bool doRope = byteMode ? (((const unsigned char*)maskPtr)[tn] != 0)
                                 : (((const u32*)maskPtr)[tn] != 0u);
    float c = 1.f, s = 0.f;
    if (doRope) {
      float ph;
      if (j < 12)      ph = px[tn * 12 + j];
      else if (j < 24) ph = py[tn * 12 + (j - 12)];
      else             ph = psp[tn * 8 + (j - 24)];
      c = __cosf(ph);
      s = __sinf(ph);
    }
    cs_tab[idx] = c;
    sn_tab[idx] = s;
    return;
  }
  const int tb = blk - 2560;
  const int bx = tb & 127, by = tb >> 7;
  const float* W;
  f16* Wt;
  int Ccols, c0;
  if (bx < 96) { W = Wqkv;  Wt = Wqkvt;  Ccols = 3072; c0 = bx * 32; }
  else         { W = Wproj; Wt = Wprojt; Ccols = 1024; c0 = (bx - 96) * 32; }
  const int R = 1024;
  const int r0 = by * 32;
  const int tx = tid & 31, ty = tid >> 5;
#pragma unroll
  for (int k = 0; k < 4; ++k)
    tile[ty + 8 * k][tx] = (f16)W[(size_t)(r0 + ty + 8 * k) * Ccols + c0 + tx];
  __syncthreads();
#pragma unroll
  for (int k = 0; k < 4; ++k)
    Wt[(size_t)(c0 + ty + 8 * k) * R + r0 + tx] = tile[tx][ty + 8 * k];
}

// ---------------------------------------------------------------- fused QKV GEMM + bias + rope + split (128x128 tile)
__global__ __launch_bounds__(256) void gemm_qkv(const f16* __restrict__ A,
                                                const f16* __restrict__ Bt,
                                                const float* __restrict__ bias,
                                                const float* __restrict__ cs_tab,
                                                const float* __restrict__ sn_tab,
                                                f16* __restrict__ Qh,
                                                f16* __restrict__ Kh,
                                                f16* __restrict__ Vt) {
  __shared__ __align__(16) f16 smem[128 * 130];
  f16* const As = smem;
  f16* const Bs = smem + 8192;
  const int K = 1024, Ncols = 3072;
  const int tid = threadIdx.x;
  const int lane = tid & 63;
  const int wv = tid >> 6;
  const int wm = wv >> 1, wn = wv & 1;
  const int nTN = Ncols >> 7;
  int bid = blockIdx.x;
  const int cpx = gridDim.x >> 3;
  bid = (bid & 7) * cpx + (bid >> 3);
  const int tM = bid / nTN, tN = bid % nTN;
  const int rowBase = tM << 7, colBase = tN << 7;
  const int cl = lane & 15, cg = lane >> 4;

  f32x4 acc[4][4];
#pragma unroll
  for (int i = 0; i < 4; ++i)
#pragma unroll
    for (int j = 0; j < 4; ++j) acc[i][j] = (f32x4){0.f, 0.f, 0.f, 0.f};

  const int sR = tid >> 3, sC = tid & 7;

#pragma unroll 4
  for (int k0 = 0; k0 < K; k0 += 64) {
#pragma unroll
    for (int is = 0; is < 4; ++is) {
      const int r = is * 32 + sR;
      const int sc = sC ^ (r & 7);
      gload_lds16(A + (size_t)(rowBase + r) * K + k0 + sc * 8, As + is * 2048 + tid * 8);
    }
#pragma unroll
    for (int is = 0; is < 4; ++is) {
      const int r = is * 32 + sR;
      const int sc = sC ^ (r & 7);
      gload_lds16(Bt + (size_t)(colBase + r) * K + k0 + sc * 8, Bs + is * 2048 + tid * 8);
    }
    asm volatile("s_waitcnt vmcnt(0)" ::: "memory");
    __syncthreads();

#pragma unroll
    for (int ks = 0; ks < 2; ++ks) {
      f16x8 af[4], bf[4];
#pragma unroll
      for (int m = 0; m < 4; ++m) {
        const int row = wm * 64 + m * 16 + cl;
        const int ck = (ks * 4 + cg) ^ (row & 7);
        af[m] = *(const f16x8*)(As + row * 64 + ck * 8);
      }
#pragma unroll
      for (int n = 0; n < 4; ++n) {
        const int row = wn * 64 + n * 16 + cl;
        const int ck = (ks * 4 + cg) ^ (row & 7);
        bf[n] = *(const f16x8*)(Bs + row * 64 + ck * 8);
      }
#pragma unroll
      for (int m = 0; m < 4; ++m)
#pragma unroll
        for (int n = 0; n < 4; ++n)
          acc[m][n] = __builtin_amdgcn_mfma_f32_16x16x32_f16(af[m], bf[n], acc[m][n], 0, 0, 0);
    }
    __syncthreads();
  }

#pragma unroll
  for (int m = 0; m < 4; ++m)
#pragma unroll
    for (int n = 0; n < 4; ++n) {
      const int lc = wn * 64 + n * 16 + cl;
      const float bz = bias[colBase + lc];
#pragma unroll
      for (int reg = 0; reg < 4; ++reg) {
        const int lr = wm * 64 + m * 16 + cg * 4 + reg;
        smem[lr * 130 + lc] = (f16)(acc[m][n][reg] + bz);
      }
    }
  __syncthreads();

  const int sec = colBase >> 10;
  const int h0 = (colBase & 1023) >> 6;
  const int bb = rowBase >> 11;
  const int nbase = rowBase & 2047;

  if (sec < 2) {
    const int lr = tid >> 1, hh = tid & 1;
    const int n = nbase + lr;
    const int h = h0 + hh;
    const f16* srcrow = smem + lr * 130 + hh * 64;
    float t[64];
#pragma unroll
    for (int c = 0; c < 8; ++c) {
      f16x8 v = *(const f16x8*)(srcrow + c * 8);
#pragma unroll
      for (int j = 0; j < 8; ++j) t[c * 8 + j] = (float)v[j];
    }
    const float* csr = cs_tab + ((size_t)bb * N_ + n) * 32;
    const float* snr = sn_tab + ((size_t)bb * N_ + n) * 32;
    __align__(16) f16 o[64];
#pragma unroll
    for (int d = 0; d < 64; ++d) {
      int j;
      float rot;
      if (d < 24) {
        j = (d < 12) ? d : d - 12;
        rot = (d < 12) ? -t[d + 12] : t[d - 12];
      } else if (d < 48) {
        const int dd = d - 24;
        j = 12 + ((dd < 12) ? dd : dd - 12);
        rot = (dd < 12) ? -t[d + 12] : t[d - 12];
      } else {
        const int dd = d - 48;
        j = 24 + ((dd < 8) ? dd : dd - 8);
        rot = (dd < 8) ? -t[d + 8] : t[d - 8];
      }
      o[d] = (f16)(t[d] * csr[j] + rot * snr[j]);
    }
    f16* dst = (sec == 0 ? Qh : Kh) + (((size_t)(bb * H_ + h)) * N_ + n) * 64;
#pragma unroll
    for (int c = 0; c < 8; ++c) *(f16x8*)(dst + c * 8) = *(const f16x8*)(o + c * 8);
  } else {
    const int pr = tid >> 1, half = tid & 1;
    const int hh = pr >> 6, d = pr & 63;
    const int h = h0 + hh;
    __align__(16) f16 o[64];
#pragma unroll
    for (int i = 0; i < 64; ++i) o[i] = smem[(half * 64 + i) * 130 + hh * 64 + d];
    f16* dst = Vt + (((size_t)(bb * H_ + h)) * 64 + d) * N_ + nbase + half * 64;
#pragma unroll
    for (int c = 0; c < 8; ++c) *(f16x8*)(dst + c * 8) = *(const f16x8*)(o + c * 8);
  }
}

// ---------------------------------------------------------------- GEMM (f32 out) for proj
__global__ __launch_bounds__(256) void gemm_bt_f32(const f16* __restrict__ A,
                                                   const f16* __restrict__ Bt,
                                                   const float* __restrict__ bias,
                                                   float* __restrict__ Cout,
                                                   int M, int N, int K) {
  __shared__ __align__(16) f16 As[128 * 64];
  __shared__ __align__(16) f16 Bs[128 * 64];
  const int tid = threadIdx.x;
  const int lane = tid & 63;
  const int wv = tid >> 6;
  const int wm = wv >> 1, wn = wv & 1;
  const int nTN = N >> 7;
  int bid = blockIdx.x;
  const int cpx = gridDim.x >> 3;
  bid = (bid & 7) * cpx + (bid >> 3);
  const int tM = bid / nTN, tN = bid % nTN;
  const int rowBase = tM << 7, colBase = tN << 7;
  const int cl = lane & 15, cg = lane >> 4;

  f32x4 acc[4][4];
#pragma unroll
  for (int i = 0; i < 4; ++i)
#pragma unroll
    for (int j = 0; j < 4; ++j) acc[i][j] = (f32x4){0.f, 0.f, 0.f, 0.f};

  const int sR = tid >> 3, sC = tid & 7;

#pragma unroll 4
  for (int k0 = 0; k0 < K; k0 += 64) {
#pragma unroll
    for (int is = 0; is < 4; ++is) {
      const int r = is * 32 + sR;
      const int sc = sC ^ (r & 7);
      gload_lds16(A + (size_t)(rowBase + r) * K + k0 + sc * 8, As + is * 2048 + tid * 8);
    }
#pragma unroll
    for (int is = 0; is < 4; ++is) {
      const int r = is * 32 + sR;
      const int sc = sC ^ (r & 7);
      gload_lds16(Bt + (size_t)(colBase + r) * K + k0 + sc * 8, Bs + is * 2048 + tid * 8);
    }
    asm volatile("s_waitcnt vmcnt(0)" ::: "memory");
    __syncthreads();

#pragma unroll
    for (int ks = 0; ks < 2; ++ks) {
      f16x8 af[4], bf[4];
#pragma unroll
      for (int m = 0; m < 4; ++m) {
        const int row = wm * 64 + m * 16 + cl;
        const int ck = (ks * 4 + cg) ^ (row & 7);
        af[m] = *(const f16x8*)(As + row * 64 + ck * 8);
      }
#pragma unroll
      for (int n = 0; n < 4; ++n) {
        const int row = wn * 64 + n * 16 + cl;
        const int ck = (ks * 4 + cg) ^ (row & 7);
        bf[n] = *(const f16x8*)(Bs + row * 64 + ck * 8);
      }
#pragma unroll
      for (int m = 0; m < 4; ++m)
#pragma unroll
        for (int n = 0; n < 4; ++n)
          acc[m][n] = __builtin_amdgcn_mfma_f32_16x16x32_f16(af[m], bf[n], acc[m][n], 0, 0, 0);
    }
    __syncthreads();
  }

#pragma unroll
  for (int m = 0; m < 4; ++m) {
#pragma unroll
    for (int n = 0; n < 4; ++n) {
      const int gr0 = rowBase + wm * 64 + m * 16 + cg * 4;
      const int gc = colBase + wn * 64 + n * 16 + cl;
      const float bz = bias[gc];
#pragma unroll
      for (int reg = 0; reg < 4; ++reg)
        Cout[(size_t)(gr0 + reg) * N + gc] = acc[m][n][reg] + bz;
    }
  }
}

// ---------------------------------------------------------------- flash attention v8 (r23/r24, passing, 57.3us)
__global__ __launch_bounds__(512) void attn2(const f16* __restrict__ Qh,
                                             const f16* __restrict__ Kh,
                                             const f16* __restrict__ Vt,
                                             f16* __restrict__ Y) {
  __shared__ __align__(16) f16 lds_flat[3 * 8192];   // 49,152 B
  const int tid = threadIdx.x, lane = tid & 63, w = tid >> 6;   // w in 0..7
  int bid = blockIdx.x;
  bid = (bid & 7) * 32 + (bid >> 3);  // XCD-chunked swizzle (256 % 8 == 0)
  const int bh = bid >> 3, qb = bid & 7;
  const int b = bh >> 4, h = bh & 15;
  const f16* Qb = Qh + (size_t)bh * N_ * 64;
  const f16* Kb = Kh + (size_t)bh * N_ * 64;
  const f16* Vb = Vt + (size_t)bh * 64 * N_;
  const int ql = lane & 31, hi = lane >> 5;

  f16x8 qf[4];
  {
    const int qrow = qb * 256 + w * 32 + ql;
    const f16 scl = (f16)0.125f;
#pragma unroll
    for (int ks = 0; ks < 4; ++ks) {
      f16x8 v = *(const f16x8*)(Qb + (size_t)qrow * 64 + ks * 16 + hi * 8);
#pragma unroll
      for (int j = 0; j < 8; ++j) v[j] *= scl;
      qf[ks] = v;
    }
  }

  const f16x8 ones = {(f16)1, (f16)1, (f16)1, (f16)1, (f16)1, (f16)1, (f16)1, (f16)1};

  f32x16 Of[2];
  f32x16 accl;
#pragma unroll
  for (int d = 0; d < 2; ++d)
#pragma unroll
    for (int r = 0; r < 16; ++r) Of[d][r] = 0.f;
#pragma unroll
  for (int r = 0; r < 16; ++r) accl[r] = 0.f;
  float m_run = -1e30f;

  const int sr = tid >> 3, sc = tid & 7;
#define STAGE(t, bp)                                                                     \
  {                                                                                      \
    const int g = sc ^ (sr & 7);                                                         \
    gload_lds16(Kb + (size_t)((t) * 64 + sr) * 64 + g * 8, (bp) + tid * 8);              \
    gload_lds16(Vb + (size_t)sr * N_ + (t) * 64 + g * 8, (bp) + 4096 + tid * 8);         \
  }

#define CHUNK_MAX(sa, out)                                                               \
  float out;                                                                             \
  {                                                                                      \
    float t0 = max3f(sa[0], sa[1], sa[2]);                                               \
    float t1 = max3f(sa[3], sa[4], sa[5]);                                               \
    float t2 = max3f(sa[6], sa[7], sa[8]);                                               \
    float t3 = max3f(sa[9], sa[10], sa[11]);                                             \
    float t4 = max3f(sa[12], sa[13], sa[14]);                                            \
    out = max3f(max3f(t0, t1, t2), max3f(t3, t4, sa[15]), -1e30f);                       \
  }

#define CHUNK_EXP(sa)                                                                    \
  {                                                                                      \
    _Pragma("unroll") for (int r = 0; r < 16; ++r) sa[r] = __expf(sa[r] - m_run);        \
  }

#define PV_CHUNK(sa, s)                                                                  \
  {                                                                                      \
    u32 pw[8];                                                                           \
    _Pragma("unroll") for (int tt = 0; tt < 8; ++tt)                                     \
      pw[tt] = pack_f16(sa[2 * tt], sa[2 * tt + 1]);                                     \
    _Pragma("unroll") for (int kk = 0; kk < 2; ++kk) {                                   \
      u32 a0 = pw[4 * kk], a1 = pw[4 * kk + 1];                                          \
      u32 b0 = pw[4 * kk + 2], b1 = pw[4 * kk + 3];                                      \
      asm volatile("v_permlane32_swap_b32 %0, %1" : "+v"(a0), "+v"(b0));                 \
      asm volatile("v_permlane32_swap_b32 %0, %1" : "+v"(a1), "+v"(b1));                 \
      union { u32 u[4]; f16x8 v; } pf;                                                   \
      pf.u[0] = a0; pf.u[1] = a1; pf.u[2] = b0; pf.u[3] = b1;                            \
      __builtin_amdgcn_s_setprio(1);                                                     \
      _Pragma("unroll") for (int df = 0; df < 2; ++df) {                                 \
        const int d = df * 32 + ql;                                                      \
        f16x8 vf = *(const f16x8*)(Vs + d * 64 + (((s) * 4 + kk * 2 + hi) ^ (d & 7)) * 8);\
        Of[df] = __builtin_amdgcn_mfma_f32_32x32x16_f16(vf, pf.v, Of[df], 0, 0, 0);      \
      }                                                                                  \
      accl = __builtin_amdgcn_mfma_f32_32x32x16_f16(ones, pf.v, accl, 0, 0, 0);          \
      __builtin_amdgcn_s_setprio(0);                                                     \
    }                                                                                    \
  }

  f16* const base = &lds_flat[0];
  STAGE(0, base);
  STAGE(1, base + 8192);
  asm volatile("s_waitcnt vmcnt(2)" ::: "memory");
  __builtin_amdgcn_s_barrier();

  f16* curp = base;
  f16* stagep = base + 16384;
  for (int t = 0; t < N_ / 64; ++t) {
    if (t < N_ / 64 - 2) STAGE(t + 2, stagep);
    const f16* Ks = curp;
    const f16* Vs = curp + 4096;

    f32x16 sa0, sa1;
#pragma unroll
    for (int r = 0; r < 16; ++r) { sa0[r] = 0.f; sa1[r] = 0.f; }
    const int krow0 = ql, krow1 = 32 + ql;
    __builtin_amdgcn_s_setprio(1);
#pragma unroll
    for (int ks = 0; ks < 4; ++ks) {
      f16x8 kf = *(const f16x8*)(Ks + krow0 * 64 + ((ks * 2 + hi) ^ (krow0 & 7)) * 8);
      sa0 = __builtin_amdgcn_mfma_f32_32x32x16_f16(kf, qf[ks], sa0, 0, 0, 0);
    }
#pragma unroll
    for (int ks = 0; ks < 4; ++ks) {
      f16x8 kf = *(const f16x8*)(Ks + krow1 * 64 + ((ks * 2 + hi) ^ (krow1 & 7)) * 8);
      sa1 = __builtin_amdgcn_mfma_f32_32x32x16_f16(kf, qf[ks], sa1, 0, 0, 0);
    }
    __builtin_amdgcn_s_setprio(0);

    CHUNK_MAX(sa0, p0);
    CHUNK_MAX(sa1, p1);
    float pmax = fmaxf(p0, p1);
    pmax = fmaxf(pmax, __shfl_xor(pmax, 32));
    if (__any(pmax > m_run + 8.0f)) {
      const float mnew = fmaxf(m_run, pmax);
      const float corr = __expf(m_run - mnew);
      accl[0] *= corr;
#pragma unroll
      for (int d = 0; d < 2; ++d)
#pragma unroll
        for (int r = 0; r < 16; ++r) Of[d][r] *= corr;
      m_run = mnew;
    }
    CHUNK_EXP(sa0);
    CHUNK_EXP(sa1);

    PV_CHUNK(sa0, 0);
    PV_CHUNK(sa1, 1);

    if (t < N_ / 64 - 2)
      asm volatile("s_waitcnt vmcnt(2) lgkmcnt(0)" ::: "memory");
    else if (t < N_ / 64 - 1)
      asm volatile("s_waitcnt vmcnt(0) lgkmcnt(0)" ::: "memory");
    else
      asm volatile("s_waitcnt lgkmcnt(0)" ::: "memory");
    __builtin_amdgcn_s_barrier();
    curp = (curp == base + 16384) ? base : curp + 8192;
    stagep = (stagep == base + 16384) ? base : stagep + 8192;
  }

  const float inv = 1.0f / accl[0];
  f16* Ow = base + w * (32 * 72);
#pragma unroll
  for (int df = 0; df < 2; ++df)
#pragma unroll
    for (int g = 0; g < 4; ++g) {
      f16x4 ov;
#pragma unroll
      for (int e = 0; e < 4; ++e) ov[e] = (f16)(Of[df][g * 4 + e] * inv);
      *(f16x4*)(Ow + ql * 72 + df * 32 + g * 8 + hi * 4) = ov;
    }
  __syncthreads();
  const int rr = lane >> 1, half = lane & 1;
  const f16* srcp = Ow + rr * 72 + half * 32;
  const int nglob = qb * 256 + w * 32 + rr;
  f16* dst = Y + ((size_t)b * N_ + nglob) * C_ + h * 64 + half * 32;
#pragma unroll
  for (int c2 = 0; c2 < 4; ++c2)
    *(f16x8*)(dst + c2 * 8) = *(const f16x8*)(srcp + c2 * 8);
}

// ---------------------------------------------------------------- launch
extern "C" void kernel_launch(void* const* d_in, const int* in_sizes, int n_in,
                              void* d_out, int out_size, void* d_ws, size_t ws_size,
                              hipStream_t stream) {
  const float* x = (const float*)d_in[0];
  const float* px = (const float*)d_in[1];
  const float* py = (const float*)d_in[2];
  const float* psp = (const float*)d_in[3];
  const void* mask = (const void*)d_in[4];
  const float* Wqkv = (const float*)d_in[5];
  const float* bqkv = (const float*)d_in[6];
  const float* Wproj = (const float*)d_in[7];
  const float* bproj = (const float*)d_in[8];
  float* out = (float*)d_out;
  char* ws = (char*)d_ws;

  f16* xh     = (f16*)(ws + 0);           //  8,388,608
  f16* Wqkvt  = (f16*)(ws + 8388608);     //  6,291,456
  f16* Wprojt = (f16*)(ws + 14680064);    //  2,097,152
  f16* Qh     = (f16*)(ws + 41943040);    //  8,388,608
  f16* Kh     = (f16*)(ws + 50331648);    //  8,388,608
  f16* Vt     = (f16*)(ws + 58720256);    //  8,388,608
  f16* Yh     = (f16*)(ws + 67108864);    //  8,388,608
  float* cs_tab = (float*)(ws + 16777216);             // 524,288
  float* sn_tab = (float*)(ws + 17301504);             // 524,288

  prep<<<2048 + 512 + 4096, 256, 0, stream>>>(x, xh, px, py, psp, mask,
                                              cs_tab, sn_tab, Wqkv, Wproj,
                                              Wqkvt, Wprojt);
  gemm_qkv<<<(4096 / 128) * (3072 / 128), 256, 0, stream>>>(
      xh, Wqkvt, bqkv, cs_tab, sn_tab, Qh, Kh, Vt);
  attn2<<<256, 512, 0, stream>>>(Qh, Kh, Vt, Yh);
  gemm_bt_f32<<<(4096 / 128) * (1024 / 128), 256, 0, stream>>>(
      Yh, Wprojt, bproj, out, 4096, 1024, 1024);
}

// Round 26
// 129.536 us; speedup vs baseline: 1.0467x; 1.0060x over previous
//
#include <hip/hip_runtime.h>
#include <hip/hip_fp16.h>

typedef _Float16 f16;
typedef unsigned int u32;
typedef _Float16 f16x4 __attribute__((ext_vector_type(4)));
typedef _Float16 f16x8 __attribute__((ext_vector_type(8)));
typedef float f32x4 __attribute__((ext_vector_type(4)));
typedef float f32x16 __attribute__((ext_vector_type(16)));

#define B_  2
#define N_  2048
#define C_  1024
#define H_  16
#define HD_ 64

// ---------------------------------------------------------------- helpers
__device__ __forceinline__ void gload_lds16(const void* g, void* l) {
  __builtin_amdgcn_global_load_lds((const __attribute__((address_space(1))) u32*)g,
                                   (__attribute__((address_space(3))) u32*)l,
                                   16, 0, 0);
}

__device__ __forceinline__ u32 pack_f16(float a, float b) {
  auto h2 = __builtin_amdgcn_cvt_pkrtz(a, b);   // __fp16 ext_vector(2)
  return __builtin_bit_cast(u32, h2);
}

__device__ __forceinline__ float max3f(float a, float b, float c) {
  return fmaxf(fmaxf(a, b), c);   // clang fuses to v_max3_f32
}

// ---------------------------------------------------------------- unified prep kernel
__global__ __launch_bounds__(256) void prep(const float* __restrict__ x,
                                            f16* __restrict__ xh,
                                            const float* __restrict__ px,
                                            const float* __restrict__ py,
                                            const float* __restrict__ psp,
                                            const void* __restrict__ maskPtr,
                                            float* __restrict__ cs_tab,
                                            float* __restrict__ sn_tab,
                                            const float* __restrict__ Wqkv,
                                            const float* __restrict__ Wproj,
                                            f16* __restrict__ Wqkvt,
                                            f16* __restrict__ Wprojt) {
  __shared__ __align__(16) f16 tile[32][34];
  __shared__ int bad;
  const int blk = blockIdx.x;
  const int tid = threadIdx.x;

  if (blk < 2048) {
    const int i = blk * 256 + tid;
    const float4 a = ((const float4*)x)[i * 2];
    const float4 b = ((const float4*)x)[i * 2 + 1];
    f16x8 o = {(f16)a.x, (f16)a.y, (f16)a.z, (f16)a.w,
               (f16)b.x, (f16)b.y, (f16)b.z, (f16)b.w};
    ((f16x8*)xh)[i] = o;
    return;
  }
  if (blk < 2560) {
    if (tid == 0) bad = 0;
    __syncthreads();
    {
      const u32* mw = (const u32*)maskPtr;
      int v = 0;
#pragma unroll
      for (int k = 0; k < 4; ++k) {
        u32 wv_ = mw[tid * 4 + k];
        if (wv_ != 0u && wv_ != 1u && wv_ != 0x3F800000u) v = 1;
      }
      if (v) atomicOr(&bad, 1);
    }
    __syncthreads();
    const int byteMode = bad;
    const int idx = (blk - 2048) * 256 + tid;
    const int j = idx & 31, tn = idx >> 5;
    const bool doRope = byteMode ? (((const unsigned char*)maskPtr)[tn] != 0)
                                 : (((const u32*)maskPtr)[tn] != 0u);
    float c = 1.f, s = 0.f;
    if (doRope) {
      float ph;
      if (j < 12)      ph = px[tn * 12 + j];
      else if (j < 24) ph = py[tn * 12 + (j - 12)];
      else             ph = psp[tn * 8 + (j - 24)];
      c = __cosf(ph);
      s = __sinf(ph);
    }
    cs_tab[idx] = c;
    sn_tab[idx] = s;
    return;
  }
  const int tb = blk - 2560;
  const int bx = tb & 127, by = tb >> 7;
  const float* W;
  f16* Wt;
  int Ccols, c0;
  if (bx < 96) { W = Wqkv;  Wt = Wqkvt;  Ccols = 3072; c0 = bx * 32; }
  else         { W = Wproj; Wt = Wprojt; Ccols = 1024; c0 = (bx - 96) * 32; }
  const int R = 1024;
  const int r0 = by * 32;
  const int tx = tid & 31, ty = tid >> 5;
#pragma unroll
  for (int k = 0; k < 4; ++k)
    tile[ty + 8 * k][tx] = (f16)W[(size_t)(r0 + ty + 8 * k) * Ccols + c0 + tx];
  __syncthreads();
#pragma unroll
  for (int k = 0; k < 4; ++k)
    Wt[(size_t)(c0 + ty + 8 * k) * R + r0 + tx] = tile[tx][ty + 8 * k];
}

// ---------------------------------------------------------------- fused QKV GEMM + bias + rope + split (128x128 tile)
__global__ __launch_bounds__(256) void gemm_qkv(const f16* __restrict__ A,
                                                const f16* __restrict__ Bt,
                                                const float* __restrict__ bias,
                                                const float* __restrict__ cs_tab,
                                                const float* __restrict__ sn_tab,
                                                f16* __restrict__ Qh,
                                                f16* __restrict__ Kh,
                                                f16* __restrict__ Vt) {
  __shared__ __align__(16) f16 smem[128 * 130];
  f16* const As = smem;
  f16* const Bs = smem + 8192;
  const int K = 1024, Ncols = 3072;
  const int tid = threadIdx.x;
  const int lane = tid & 63;
  const int wv = tid >> 6;
  const int wm = wv >> 1, wn = wv & 1;
  const int nTN = Ncols >> 7;
  int bid = blockIdx.x;
  const int cpx = gridDim.x >> 3;
  bid = (bid & 7) * cpx + (bid >> 3);
  const int tM = bid / nTN, tN = bid % nTN;
  const int rowBase = tM << 7, colBase = tN << 7;
  const int cl = lane & 15, cg = lane >> 4;

  f32x4 acc[4][4];
#pragma unroll
  for (int i = 0; i < 4; ++i)
#pragma unroll
    for (int j = 0; j < 4; ++j) acc[i][j] = (f32x4){0.f, 0.f, 0.f, 0.f};

  const int sR = tid >> 3, sC = tid & 7;

#pragma unroll 4
  for (int k0 = 0; k0 < K; k0 += 64) {
#pragma unroll
    for (int is = 0; is < 4; ++is) {
      const int r = is * 32 + sR;
      const int sc = sC ^ (r & 7);
      gload_lds16(A + (size_t)(rowBase + r) * K + k0 + sc * 8, As + is * 2048 + tid * 8);
    }
#pragma unroll
    for (int is = 0; is < 4; ++is) {
      const int r = is * 32 + sR;
      const int sc = sC ^ (r & 7);
      gload_lds16(Bt + (size_t)(colBase + r) * K + k0 + sc * 8, Bs + is * 2048 + tid * 8);
    }
    asm volatile("s_waitcnt vmcnt(0)" ::: "memory");
    __syncthreads();

#pragma unroll
    for (int ks = 0; ks < 2; ++ks) {
      f16x8 af[4], bf[4];
#pragma unroll
      for (int m = 0; m < 4; ++m) {
        const int row = wm * 64 + m * 16 + cl;
        const int ck = (ks * 4 + cg) ^ (row & 7);
        af[m] = *(const f16x8*)(As + row * 64 + ck * 8);
      }
#pragma unroll
      for (int n = 0; n < 4; ++n) {
        const int row = wn * 64 + n * 16 + cl;
        const int ck = (ks * 4 + cg) ^ (row & 7);
        bf[n] = *(const f16x8*)(Bs + row * 64 + ck * 8);
      }
#pragma unroll
      for (int m = 0; m < 4; ++m)
#pragma unroll
        for (int n = 0; n < 4; ++n)
          acc[m][n] = __builtin_amdgcn_mfma_f32_16x16x32_f16(af[m], bf[n], acc[m][n], 0, 0, 0);
    }
    __syncthreads();
  }

#pragma unroll
  for (int m = 0; m < 4; ++m)
#pragma unroll
    for (int n = 0; n < 4; ++n) {
      const int lc = wn * 64 + n * 16 + cl;
      const float bz = bias[colBase + lc];
#pragma unroll
      for (int reg = 0; reg < 4; ++reg) {
        const int lr = wm * 64 + m * 16 + cg * 4 + reg;
        smem[lr * 130 + lc] = (f16)(acc[m][n][reg] + bz);
      }
    }
  __syncthreads();

  const int sec = colBase >> 10;
  const int h0 = (colBase & 1023) >> 6;
  const int bb = rowBase >> 11;
  const int nbase = rowBase & 2047;

  if (sec < 2) {
    const int lr = tid >> 1, hh = tid & 1;
    const int n = nbase + lr;
    const int h = h0 + hh;
    const f16* srcrow = smem + lr * 130 + hh * 64;
    float t[64];
#pragma unroll
    for (int c = 0; c < 8; ++c) {
      f16x8 v = *(const f16x8*)(srcrow + c * 8);
#pragma unroll
      for (int j = 0; j < 8; ++j) t[c * 8 + j] = (float)v[j];
    }
    const float* csr = cs_tab + ((size_t)bb * N_ + n) * 32;
    const float* snr = sn_tab + ((size_t)bb * N_ + n) * 32;
    __align__(16) f16 o[64];
#pragma unroll
    for (int d = 0; d < 64; ++d) {
      int j;
      float rot;
      if (d < 24) {
        j = (d < 12) ? d : d - 12;
        rot = (d < 12) ? -t[d + 12] : t[d - 12];
      } else if (d < 48) {
        const int dd = d - 24;
        j = 12 + ((dd < 12) ? dd : dd - 12);
        rot = (dd < 12) ? -t[d + 12] : t[d - 12];
      } else {
        const int dd = d - 48;
        j = 24 + ((dd < 8) ? dd : dd - 8);
        rot = (dd < 8) ? -t[d + 8] : t[d - 8];
      }
      o[d] = (f16)(t[d] * csr[j] + rot * snr[j]);
    }
    f16* dst = (sec == 0 ? Qh : Kh) + (((size_t)(bb * H_ + h)) * N_ + n) * 64;
#pragma unroll
    for (int c = 0; c < 8; ++c) *(f16x8*)(dst + c * 8) = *(const f16x8*)(o + c * 8);
  } else {
    const int pr = tid >> 1, half = tid & 1;
    const int hh = pr >> 6, d = pr & 63;
    const int h = h0 + hh;
    __align__(16) f16 o[64];
#pragma unroll
    for (int i = 0; i < 64; ++i) o[i] = smem[(half * 64 + i) * 130 + hh * 64 + d];
    f16* dst = Vt + (((size_t)(bb * H_ + h)) * 64 + d) * N_ + nbase + half * 64;
#pragma unroll
    for (int c = 0; c < 8; ++c) *(f16x8*)(dst + c * 8) = *(const f16x8*)(o + c * 8);
  }
}

// ---------------------------------------------------------------- GEMM (f32 out) for proj
__global__ __launch_bounds__(256) void gemm_bt_f32(const f16* __restrict__ A,
                                                   const f16* __restrict__ Bt,
                                                   const float* __restrict__ bias,
                                                   float* __restrict__ Cout,
                                                   int M, int N, int K) {
  __shared__ __align__(16) f16 As[128 * 64];
  __shared__ __align__(16) f16 Bs[128 * 64];
  const int tid = threadIdx.x;
  const int lane = tid & 63;
  const int wv = tid >> 6;
  const int wm = wv >> 1, wn = wv & 1;
  const int nTN = N >> 7;
  int bid = blockIdx.x;
  const int cpx = gridDim.x >> 3;
  bid = (bid & 7) * cpx + (bid >> 3);
  const int tM = bid / nTN, tN = bid % nTN;
  const int rowBase = tM << 7, colBase = tN << 7;
  const int cl = lane & 15, cg = lane >> 4;

  f32x4 acc[4][4];
#pragma unroll
  for (int i = 0; i < 4; ++i)
#pragma unroll
    for (int j = 0; j < 4; ++j) acc[i][j] = (f32x4){0.f, 0.f, 0.f, 0.f};

  const int sR = tid >> 3, sC = tid & 7;

#pragma unroll 4
  for (int k0 = 0; k0 < K; k0 += 64) {
#pragma unroll
    for (int is = 0; is < 4; ++is) {
      const int r = is * 32 + sR;
      const int sc = sC ^ (r & 7);
      gload_lds16(A + (size_t)(rowBase + r) * K + k0 + sc * 8, As + is * 2048 + tid * 8);
    }
#pragma unroll
    for (int is = 0; is < 4; ++is) {
      const int r = is * 32 + sR;
      const int sc = sC ^ (r & 7);
      gload_lds16(Bt + (size_t)(colBase + r) * K + k0 + sc * 8, Bs + is * 2048 + tid * 8);
    }
    asm volatile("s_waitcnt vmcnt(0)" ::: "memory");
    __syncthreads();

#pragma unroll
    for (int ks = 0; ks < 2; ++ks) {
      f16x8 af[4], bf[4];
#pragma unroll
      for (int m = 0; m < 4; ++m) {
        const int row = wm * 64 + m * 16 + cl;
        const int ck = (ks * 4 + cg) ^ (row & 7);
        af[m] = *(const f16x8*)(As + row * 64 + ck * 8);
      }
#pragma unroll
      for (int n = 0; n < 4; ++n) {
        const int row = wn * 64 + n * 16 + cl;
        const int ck = (ks * 4 + cg) ^ (row & 7);
        bf[n] = *(const f16x8*)(Bs + row * 64 + ck * 8);
      }
#pragma unroll
      for (int m = 0; m < 4; ++m)
#pragma unroll
        for (int n = 0; n < 4; ++n)
          acc[m][n] = __builtin_amdgcn_mfma_f32_16x16x32_f16(af[m], bf[n], acc[m][n], 0, 0, 0);
    }
    __syncthreads();
  }

#pragma unroll
  for (int m = 0; m < 4; ++m) {
#pragma unroll
    for (int n = 0; n < 4; ++n) {
      const int gr0 = rowBase + wm * 64 + m * 16 + cg * 4;
      const int gc = colBase + wn * 64 + n * 16 + cl;
      const float bz = bias[gc];
#pragma unroll
      for (int reg = 0; reg < 4; ++reg)
        Cout[(size_t)(gr0 + reg) * N + gc] = acc[m][n][reg] + bz;
    }
  }
}

// ---------------------------------------------------------------- flash attention v8 + unroll-3 t-loop
// Period-3 buffer rotation becomes statically resolvable per unrolled body:
// removes pointer-select chain, enables immediate-offset ds addressing.
__global__ __launch_bounds__(512) void attn2(const f16* __restrict__ Qh,
                                             const f16* __restrict__ Kh,
                                             const f16* __restrict__ Vt,
                                             f16* __restrict__ Y) {
  __shared__ __align__(16) f16 lds_flat[3 * 8192];   // 49,152 B
  const int tid = threadIdx.x, lane = tid & 63, w = tid >> 6;   // w in 0..7
  int bid = blockIdx.x;
  bid = (bid & 7) * 32 + (bid >> 3);  // XCD-chunked swizzle (256 % 8 == 0)
  const int bh = bid >> 3, qb = bid & 7;
  const int b = bh >> 4, h = bh & 15;
  const f16* Qb = Qh + (size_t)bh * N_ * 64;
  const f16* Kb = Kh + (size_t)bh * N_ * 64;
  const f16* Vb = Vt + (size_t)bh * 64 * N_;
  const int ql = lane & 31, hi = lane >> 5;

  f16x8 qf[4];
  {
    const int qrow = qb * 256 + w * 32 + ql;
    const f16 scl = (f16)0.125f;
#pragma unroll
    for (int ks = 0; ks < 4; ++ks) {
      f16x8 v = *(const f16x8*)(Qb + (size_t)qrow * 64 + ks * 16 + hi * 8);
#pragma unroll
      for (int j = 0; j < 8; ++j) v[j] *= scl;
      qf[ks] = v;
    }
  }

  const f16x8 ones = {(f16)1, (f16)1, (f16)1, (f16)1, (f16)1, (f16)1, (f16)1, (f16)1};

  f32x16 Of[2];
  f32x16 accl;
#pragma unroll
  for (int d = 0; d < 2; ++d)
#pragma unroll
    for (int r = 0; r < 16; ++r) Of[d][r] = 0.f;
#pragma unroll
  for (int r = 0; r < 16; ++r) accl[r] = 0.f;
  float m_run = -1e30f;

  const int sr = tid >> 3, sc = tid & 7;
#define STAGE(t, bp)                                                                     \
  {                                                                                      \
    const int g = sc ^ (sr & 7);                                                         \
    gload_lds16(Kb + (size_t)((t) * 64 + sr) * 64 + g * 8, (bp) + tid * 8);              \
    gload_lds16(Vb + (size_t)sr * N_ + (t) * 64 + g * 8, (bp) + 4096 + tid * 8);         \
  }

#define CHUNK_MAX(sa, out)                                                               \
  float out;                                                                             \
  {                                                                                      \
    float t0 = max3f(sa[0], sa[1], sa[2]);                                               \
    float t1 = max3f(sa[3], sa[4], sa[5]);                                               \
    float t2 = max3f(sa[6], sa[7], sa[8]);                                               \
    float t3 = max3f(sa[9], sa[10], sa[11]);                                             \
    float t4 = max3f(sa[12], sa[13], sa[14]);                                            \
    out = max3f(max3f(t0, t1, t2), max3f(t3, t4, sa[15]), -1e30f);                       \
  }

#define CHUNK_EXP(sa)                                                                    \
  {                                                                                      \
    _Pragma("unroll") for (int r = 0; r < 16; ++r) sa[r] = __expf(sa[r] - m_run);        \
  }

#define PV_CHUNK(sa, s, Vs)                                                              \
  {                                                                                      \
    u32 pw[8];                                                                           \
    _Pragma("unroll") for (int tt = 0; tt < 8; ++tt)                                     \
      pw[tt] = pack_f16(sa[2 * tt], sa[2 * tt + 1]);                                     \
    _Pragma("unroll") for (int kk = 0; kk < 2; ++kk) {                                   \
      u32 a0 = pw[4 * kk], a1 = pw[4 * kk + 1];                                          \
      u32 b0 = pw[4 * kk + 2], b1 = pw[4 * kk + 3];                                      \
      asm volatile("v_permlane32_swap_b32 %0, %1" : "+v"(a0), "+v"(b0));                 \
      asm volatile("v_permlane32_swap_b32 %0, %1" : "+v"(a1), "+v"(b1));                 \
      union { u32 u[4]; f16x8 v; } pf;                                                   \
      pf.u[0] = a0; pf.u[1] = a1; pf.u[2] = b0; pf.u[3] = b1;                            \
      __builtin_amdgcn_s_setprio(1);                                                     \
      _Pragma("unroll") for (int df = 0; df < 2; ++df) {                                 \
        const int d = df * 32 + ql;                                                      \
        f16x8 vf = *(const f16x8*)((Vs) + d * 64 + (((s) * 4 + kk * 2 + hi) ^ (d & 7)) * 8);\
        Of[df] = __builtin_amdgcn_mfma_f32_32x32x16_f16(vf, pf.v, Of[df], 0, 0, 0);      \
      }                                                                                  \
      accl = __builtin_amdgcn_mfma_f32_32x32x16_f16(ones, pf.v, accl, 0, 0, 0);          \
      __builtin_amdgcn_s_setprio(0);                                                     \
    }                                                                                    \
  }

// one full tile body with buffer indices known at unroll time
#define TILE_BODY(t, curb, stgb)                                                         \
  {                                                                                      \
    if ((t) < N_ / 64 - 2) STAGE((t) + 2, base + (stgb) * 8192);                         \
    const f16* Ks = base + (curb) * 8192;                                                \
    const f16* Vs = base + (curb) * 8192 + 4096;                                         \
    f32x16 sa0, sa1;                                                                     \
    _Pragma("unroll") for (int r = 0; r < 16; ++r) { sa0[r] = 0.f; sa1[r] = 0.f; }       \
    const int krow0 = ql, krow1 = 32 + ql;                                               \
    __builtin_amdgcn_s_setprio(1);                                                       \
    _Pragma("unroll") for (int ks = 0; ks < 4; ++ks) {                                   \
      f16x8 kf = *(const f16x8*)(Ks + krow0 * 64 + ((ks * 2 + hi) ^ (krow0 & 7)) * 8);   \
      sa0 = __builtin_amdgcn_mfma_f32_32x32x16_f16(kf, qf[ks], sa0, 0, 0, 0);            \
    }                                                                                    \
    _Pragma("unroll") for (int ks = 0; ks < 4; ++ks) {                                   \
      f16x8 kf = *(const f16x8*)(Ks + krow1 * 64 + ((ks * 2 + hi) ^ (krow1 & 7)) * 8);   \
      sa1 = __builtin_amdgcn_mfma_f32_32x32x16_f16(kf, qf[ks], sa1, 0, 0, 0);            \
    }                                                                                    \
    __builtin_amdgcn_s_setprio(0);                                                       \
    CHUNK_MAX(sa0, p0);                                                                  \
    CHUNK_MAX(sa1, p1);                                                                  \
    float pmax = fmaxf(p0, p1);                                                          \
    pmax = fmaxf(pmax, __shfl_xor(pmax, 32));                                            \
    if (__any(pmax > m_run + 8.0f)) {                                                    \
      const float mnew = fmaxf(m_run, pmax);                                             \
      const float corr = __expf(m_run - mnew);                                           \
      accl[0] *= corr;                                                                   \
      _Pragma("unroll") for (int d = 0; d < 2; ++d)                                      \
        _Pragma("unroll") for (int r = 0; r < 16; ++r) Of[d][r] *= corr;                 \
      m_run = mnew;                                                                      \
    }                                                                                    \
    CHUNK_EXP(sa0);                                                                      \
    CHUNK_EXP(sa1);                                                                      \
    PV_CHUNK(sa0, 0, Vs);                                                                \
    PV_CHUNK(sa1, 1, Vs);                                                                \
    if ((t) < N_ / 64 - 2)                                                               \
      asm volatile("s_waitcnt vmcnt(2) lgkmcnt(0)" ::: "memory");                        \
    else if ((t) < N_ / 64 - 1)                                                          \
      asm volatile("s_waitcnt vmcnt(0) lgkmcnt(0)" ::: "memory");                        \
    else                                                                                 \
      asm volatile("s_waitcnt lgkmcnt(0)" ::: "memory");                                 \
    __builtin_amdgcn_s_barrier();                                                        \
  }

  f16* const base = &lds_flat[0];
  STAGE(0, base);
  STAGE(1, base + 8192);
  asm volatile("s_waitcnt vmcnt(2)" ::: "memory");
  __builtin_amdgcn_s_barrier();

  // 32 tiles = 10 full periods of 3 + 2 remainder; buffer index = t % 3 statically
  for (int tp = 0; tp < 30; tp += 3) {
    TILE_BODY(tp + 0, 0, 2);
    TILE_BODY(tp + 1, 1, 0);
    TILE_BODY(tp + 2, 2, 1);
  }
  TILE_BODY(30, 0, 2);
  TILE_BODY(31, 1, 0);

  const float inv = 1.0f / accl[0];
  f16* Ow = base + w * (32 * 72);
#pragma unroll
  for (int df = 0; df < 2; ++df)
#pragma unroll
    for (int g = 0; g < 4; ++g) {
      f16x4 ov;
#pragma unroll
      for (int e = 0; e < 4; ++e) ov[e] = (f16)(Of[df][g * 4 + e] * inv);
      *(f16x4*)(Ow + ql * 72 + df * 32 + g * 8 + hi * 4) = ov;
    }
  __syncthreads();
  const int rr = lane >> 1, half = lane & 1;
  const f16* srcp = Ow + rr * 72 + half * 32;
  const int nglob = qb * 256 + w * 32 + rr;
  f16* dst = Y + ((size_t)b * N_ + nglob) * C_ + h * 64 + half * 32;
#pragma unroll
  for (int c2 = 0; c2 < 4; ++c2)
    *(f16x8*)(dst + c2 * 8) = *(const f16x8*)(srcp + c2 * 8);
}

// ---------------------------------------------------------------- launch
extern "C" void kernel_launch(void* const* d_in, const int* in_sizes, int n_in,
                              void* d_out, int out_size, void* d_ws, size_t ws_size,
                              hipStream_t stream) {
  const float* x = (const float*)d_in[0];
  const float* px = (const float*)d_in[1];
  const float* py = (const float*)d_in[2];
  const float* psp = (const float*)d_in[3];
  const void* mask = (const void*)d_in[4];
  const float* Wqkv = (const float*)d_in[5];
  const float* bqkv = (const float*)d_in[6];
  const float* Wproj = (const float*)d_in[7];
  const float* bproj = (const float*)d_in[8];
  float* out = (float*)d_out;
  char* ws = (char*)d_ws;

  f16* xh     = (f16*)(ws + 0);           //  8,388,608
  f16* Wqkvt  = (f16*)(ws + 8388608);     //  6,291,456
  f16* Wprojt = (f16*)(ws + 14680064);    //  2,097,152
  f16* Qh     = (f16*)(ws + 41943040);    //  8,388,608
  f16* Kh     = (f16*)(ws + 50331648);    //  8,388,608
  f16* Vt     = (f16*)(ws + 58720256);    //  8,388,608
  f16* Yh     = (f16*)(ws + 67108864);    //  8,388,608
  float* cs_tab = (float*)(ws + 16777216);             // 524,288
  float* sn_tab = (float*)(ws + 17301504);             // 524,288

  prep<<<2048 + 512 + 4096, 256, 0, stream>>>(x, xh, px, py, psp, mask,
                                              cs_tab, sn_tab, Wqkv, Wproj,
                                              Wqkvt, Wprojt);
  gemm_qkv<<<(4096 / 128) * (3072 / 128), 256, 0, stream>>>(
      xh, Wqkvt, bqkv, cs_tab, sn_tab, Qh, Kh, Vt);
  attn2<<<256, 512, 0, stream>>>(Qh, Kh, Vt, Yh);
  gemm_bt_f32<<<(4096 / 128) * (1024 / 128), 256, 0, stream>>>(
      Yh, Wprojt, bproj, out, 4096, 1024, 1024);
}